// Round 5
// baseline (324.031 us; speedup 1.0000x reference)
//
#include <hip/hip_runtime.h>
#include <math.h>

// Biquad lowpass over [B=128][T=160000] f32 (torchaudio-style, zero initial state).
//
// Parallelization: time-chunked with warm-up. The filter poles have radius
// sqrt(a2) ~ 0.4203, so state error from an unknown initial condition decays
// by 0.42x per sample; after WARM=32 samples it is ~9e-13 (far below fp32
// eps). Each thread therefore computes CHUNK=128 outputs independently after
// a 32-sample warm-up: 160000 threads total, no cross-thread dependences.
//
// Memory: 82 MB write + 102 MB read (1.25x warm-up inflation) => ~29 us
// roofline at 6.3 TB/s achievable HBM.

constexpr int T_LEN  = 160000;
constexpr int BATCH  = 128;
constexpr int CHUNK  = 128;               // outputs per thread
constexpr int WARM   = 32;                // warm-up samples (state settles)
constexpr int NCHUNK = T_LEN / CHUNK;     // 1250
constexpr int NWGRP  = WARM / 4;          // 8 warm-up float4 groups
constexpr int NMGRP  = CHUNK / 4;         // 32 main float4 groups

typedef float v4f __attribute__((ext_vector_type(4)));  // native vector: OK for
                                                        // nontemporal builtins

#define BIQUAD_STEP(XT, OUT_)                                               \
    do {                                                                    \
        float y_ = fmaf(b0, (XT),                                           \
                   fmaf(b1, x1,                                             \
                   fmaf(b2, x2,                                             \
                   fmaf(-a1, y1, -a2 * y2))));                              \
        x2 = x1; x1 = (XT); y2 = y1; y1 = y_; OUT_ = y_;                    \
    } while (0)

__global__ __launch_bounds__(256) void lowpass_kernel(
    const float* __restrict__ x, float* __restrict__ out,
    float b0, float b1, float b2, float a1, float a2)
{
    int tid = blockIdx.x * blockDim.x + threadIdx.x;
    int b = tid / NCHUNK;
    int c = tid - b * NCHUNK;

    const float* __restrict__ xp = x   + (size_t)b * T_LEN;
    float*       __restrict__ op = out + (size_t)b * T_LEN;

    const int start = c * CHUNK;      // first output sample of this thread

    float x1 = 0.f, x2 = 0.f, y1 = 0.f, y2 = 0.f;
    float sink;

    // ---- warm-up: 32 samples before `start`. For c==0 the pre-history is
    // identically zero input -> state stays exactly (0,0,0,0): skip loads.
    if (c > 0) {
        const int ws = start - WARM;
#pragma unroll
        for (int g = 0; g < NWGRP; ++g) {
            v4f xv = *reinterpret_cast<const v4f*>(xp + ws + 4 * g);
            BIQUAD_STEP(xv.x, sink);
            BIQUAD_STEP(xv.y, sink);
            BIQUAD_STEP(xv.z, sink);
            BIQUAD_STEP(xv.w, sink);
        }
        (void)sink;
    }

    // ---- main: CHUNK outputs, unconditional aligned 16B stores.
#pragma unroll
    for (int g = 0; g < NMGRP; ++g) {
        const int t = start + 4 * g;
        v4f xv = *reinterpret_cast<const v4f*>(xp + t);
        v4f yv;
        BIQUAD_STEP(xv.x, yv.x);
        BIQUAD_STEP(xv.y, yv.y);
        BIQUAD_STEP(xv.z, yv.z);
        BIQUAD_STEP(xv.w, yv.w);
        // output is never re-read: nontemporal store keeps L2 for input reuse
        __builtin_nontemporal_store(yv, reinterpret_cast<v4f*>(op + t));
    }
}

extern "C" void kernel_launch(void* const* d_in, const int* in_sizes, int n_in,
                              void* d_out, int out_size, void* d_ws, size_t ws_size,
                              hipStream_t stream) {
    const float* clip = (const float*)d_in[0];
    float* out = (float*)d_out;

    // Coefficients in double (matches Python's math-module computation),
    // rounded once to f32.
    const double SR = 44100.0, CUT = 10000.0, Q = 0.707;
    const double w0 = 2.0 * M_PI * CUT / SR;
    const double alpha = sin(w0) / (2.0 * Q);
    const double cw = cos(w0);
    const double b0d = (1.0 - cw) / 2.0;
    const double b1d = 1.0 - cw;
    const double b2d = b0d;
    const double a0d = 1.0 + alpha;
    const double a1d = -2.0 * cw;
    const double a2d = 1.0 - alpha;

    const float b0 = (float)(b0d / a0d);
    const float b1 = (float)(b1d / a0d);
    const float b2 = (float)(b2d / a0d);
    const float a1 = (float)(a1d / a0d);
    const float a2 = (float)(a2d / a0d);

    const int total = BATCH * NCHUNK;      // 160000 threads
    const int block = 256;
    const int grid  = total / block;       // 625

    lowpass_kernel<<<grid, block, 0, stream>>>(clip, out, b0, b1, b2, a1, a2);
}